// Round 9
// baseline (286.781 us; speedup 1.0000x reference)
//
#include <hip/hip_runtime.h>
#include <hip/hip_bf16.h>

typedef unsigned int uint;
typedef unsigned short ushort;
typedef __attribute__((ext_vector_type(8))) short short8v;
typedef __attribute__((ext_vector_type(4))) float f32x4;

// ---------- helpers ----------
__device__ __forceinline__ float bflo(uint u) { return __uint_as_float(u << 16); }
__device__ __forceinline__ float bfhi(uint u) { return __uint_as_float(u & 0xffff0000u); }
__device__ __forceinline__ float bfu(ushort s) { return __uint_as_float(((uint)s) << 16); }
__device__ __forceinline__ ushort f2bf(float f) {
    uint u = __float_as_uint(f);
    u += 0x7fffu + ((u >> 16) & 1u);   // RNE
    return (ushort)(u >> 16);
}
__device__ __forceinline__ uint pk2(float lo, float hi) {
    return (uint)f2bf(lo) | ((uint)f2bf(hi) << 16);
}
__device__ __forceinline__ float red4(float v) {
    v += __shfl_xor(v, 1, 64);
    v += __shfl_xor(v, 2, 64);
    return v;
}
__device__ __forceinline__ void unp8(uint4 u, float* f) {
    f[0] = bflo(u.x); f[1] = bfhi(u.x);
    f[2] = bflo(u.y); f[3] = bfhi(u.y);
    f[4] = bflo(u.z); f[5] = bfhi(u.z);
    f[6] = bflo(u.w); f[7] = bfhi(u.w);
}

// ---------- build kernels ----------
__global__ __launch_bounds__(256) void k_count(const int* __restrict__ dst,
                                               const float* __restrict__ w,
                                               int* cnt, float* sumw, int E) {
    int e = blockIdx.x * blockDim.x + threadIdx.x;
    if (e < E) {
        int d = dst[e];
        atomicAdd(&cnt[d], 1);
        atomicAdd(&sumw[d], w[e]);
    }
}

__global__ __launch_bounds__(256) void k_bsum(const int* __restrict__ cnt,
                                              int* __restrict__ bsum, int n) {
    const int i = blockIdx.x * 256 + threadIdx.x;
    const int lane = threadIdx.x & 63;
    int v = (i < n) ? cnt[i] : 0;
    v += __shfl_xor(v, 1, 64);
    v += __shfl_xor(v, 2, 64);
    v += __shfl_xor(v, 4, 64);
    v += __shfl_xor(v, 8, 64);
    v += __shfl_xor(v, 16, 64);
    v += __shfl_xor(v, 32, 64);
    __shared__ int ws[4];
    if (lane == 0) ws[threadIdx.x >> 6] = v;
    __syncthreads();
    if (threadIdx.x == 0)
        bsum[blockIdx.x] = ws[0] + ws[1] + ws[2] + ws[3];
}

__global__ __launch_bounds__(1024) void k_bscan(int* __restrict__ bsum,
                                                int* __restrict__ rowptrN, int nblk) {
    __shared__ int sd[1024];
    const int t = threadIdx.x;
    int v = (t < nblk) ? bsum[t] : 0;
    sd[t] = v;
    __syncthreads();
    for (int off = 1; off < 1024; off <<= 1) {
        int u = (t >= off) ? sd[t - off] : 0;
        __syncthreads();
        sd[t] += u;
        __syncthreads();
    }
    if (t < nblk) bsum[t] = sd[t] - v;
    if (t == 1023) *rowptrN = sd[1023];
}

__global__ __launch_bounds__(256) void k_rowptr(const int* __restrict__ cnt,
                                                const int* __restrict__ bsum,
                                                const float* __restrict__ sumw,
                                                int* __restrict__ rowptr,
                                                float* __restrict__ dinv,
                                                float* __restrict__ lattr, int n) {
    __shared__ int sd[256];
    const int t = threadIdx.x;
    const int i = blockIdx.x * 256 + t;
    int c = (i < n) ? cnt[i] : 0;
    sd[t] = c;
    __syncthreads();
    for (int off = 1; off < 256; off <<= 1) {
        int u = (t >= off) ? sd[t - off] : 0;
        __syncthreads();
        sd[t] += u;
        __syncthreads();
    }
    if (i < n) {
        rowptr[i] = bsum[blockIdx.x] + sd[t] - c;
        float sw = sumw[i];
        dinv[i] = rsqrtf(sw + 1.f);
        lattr[i] = (c > 0) ? sw / (float)c : 0.f;
    }
}

__global__ __launch_bounds__(256) void k_scatter(const int* __restrict__ src,
                                                 const int* __restrict__ dst,
                                                 const float* __restrict__ w,
                                                 const int* __restrict__ rowptr,
                                                 int* fill, int2* eSW, int E) {
    int e = blockIdx.x * blockDim.x + threadIdx.x;
    if (e < E) {
        int d = dst[e], s = src[e];
        int pos = rowptr[d] + atomicAdd(&fill[d], 1);
        eSW[pos] = make_int2(s, __float_as_int(w[e]));
    }
}

// weight conversion f32 -> bf16
__global__ __launch_bounds__(256) void k_cvtw(const float* __restrict__ W1,
                                              const float* __restrict__ Wl,
                                              const float* __restrict__ Wr,
                                              ushort* w1b, ushort* wlb, ushort* wrb) {
    int i = blockIdx.x * 256 + threadIdx.x;
    if (i < 4096) w1b[i] = f2bf(W1[i]);
    if (i < 8192) { wlb[i] = f2bf(Wl[i]); wrb[i] = f2bf(Wr[i]); }
}

// MFMA GEMM: hb[r,c] = x[r,:]·W1[c,:] (bf16 out). One wave per 16-row tile.
__global__ __launch_bounds__(256) void k_gemm_x(const float* __restrict__ X,
                                                const ushort* __restrict__ W1b,
                                                ushort* __restrict__ hb, int Mt) {
    const int wv = blockIdx.x * 4 + (threadIdx.x >> 6);
    if (wv >= Mt) return;
    const int lane = threadIdx.x & 63;
    const int r16 = lane & 15, kseg = lane >> 4;
    const float* xr = X + ((size_t)(wv * 16 + r16)) * 64 + kseg * 8;
    float4 x0 = *(const float4*)xr;
    float4 x1 = *(const float4*)(xr + 4);
    float4 x2 = *(const float4*)(xr + 32);
    float4 x3 = *(const float4*)(xr + 36);
    short8v a0, a1;
    a0[0] = (short)f2bf(x0.x); a0[1] = (short)f2bf(x0.y);
    a0[2] = (short)f2bf(x0.z); a0[3] = (short)f2bf(x0.w);
    a0[4] = (short)f2bf(x1.x); a0[5] = (short)f2bf(x1.y);
    a0[6] = (short)f2bf(x1.z); a0[7] = (short)f2bf(x1.w);
    a1[0] = (short)f2bf(x2.x); a1[1] = (short)f2bf(x2.y);
    a1[2] = (short)f2bf(x2.z); a1[3] = (short)f2bf(x2.w);
    a1[4] = (short)f2bf(x3.x); a1[5] = (short)f2bf(x3.y);
    a1[6] = (short)f2bf(x3.z); a1[7] = (short)f2bf(x3.w);
    const short8v* Wv = (const short8v*)W1b;
    f32x4 acc[4];
#pragma unroll
    for (int t = 0; t < 4; t++) acc[t] = (f32x4){0.f, 0.f, 0.f, 0.f};
#pragma unroll
    for (int t = 0; t < 4; t++) {
        int col = t * 16 + r16;
        acc[t] = __builtin_amdgcn_mfma_f32_16x16x32_bf16(a0, Wv[col * 8 + kseg], acc[t], 0, 0, 0);
        acc[t] = __builtin_amdgcn_mfma_f32_16x16x32_bf16(a1, Wv[col * 8 + 4 + kseg], acc[t], 0, 0, 0);
    }
#pragma unroll
    for (int t = 0; t < 4; t++)
#pragma unroll
        for (int i = 0; i < 4; i++)
            hb[((size_t)(wv * 16 + kseg * 4 + i)) * 64 + t * 16 + r16] = f2bf(acc[t][i]);
}

// MFMA dual GEMM: YL/YR[r,c] = A[r,:]·WL/WR[c,:] + BL/BR. A bf16 [M,64].
__global__ __launch_bounds__(256) void k_gemm_lr(const ushort* __restrict__ Ab,
                                                 const ushort* __restrict__ WLb,
                                                 const float* __restrict__ BL,
                                                 const ushort* __restrict__ WRb,
                                                 const float* __restrict__ BR,
                                                 ushort* __restrict__ YL,
                                                 ushort* __restrict__ YR, int Mt) {
    const int wv = blockIdx.x * 4 + (threadIdx.x >> 6);
    if (wv >= Mt) return;
    const int lane = threadIdx.x & 63;
    const int r16 = lane & 15, kseg = lane >> 4;
    const short8v* arow = (const short8v*)(Ab + ((size_t)(wv * 16 + r16)) * 64);
    short8v a0 = arow[kseg], a1 = arow[4 + kseg];
    const short8v* WvL = (const short8v*)WLb;
    const short8v* WvR = (const short8v*)WRb;
    f32x4 accL[8], accR[8];
#pragma unroll
    for (int t = 0; t < 8; t++) {
        accL[t] = (f32x4){0.f, 0.f, 0.f, 0.f};
        accR[t] = (f32x4){0.f, 0.f, 0.f, 0.f};
    }
#pragma unroll
    for (int t = 0; t < 8; t++) {
        int col = t * 16 + r16;
        accL[t] = __builtin_amdgcn_mfma_f32_16x16x32_bf16(a0, WvL[col * 8 + kseg], accL[t], 0, 0, 0);
        accL[t] = __builtin_amdgcn_mfma_f32_16x16x32_bf16(a1, WvL[col * 8 + 4 + kseg], accL[t], 0, 0, 0);
        accR[t] = __builtin_amdgcn_mfma_f32_16x16x32_bf16(a0, WvR[col * 8 + kseg], accR[t], 0, 0, 0);
        accR[t] = __builtin_amdgcn_mfma_f32_16x16x32_bf16(a1, WvR[col * 8 + 4 + kseg], accR[t], 0, 0, 0);
    }
#pragma unroll
    for (int t = 0; t < 8; t++) {
        int col = t * 16 + r16;
        float blv = BL[col], brv = BR[col];
#pragma unroll
        for (int i = 0; i < 4; i++) {
            size_t row = (size_t)(wv * 16 + kseg * 4 + i);
            YL[row * 128 + col] = f2bf(accL[t][i] + blv);
            YR[row * 128 + col] = f2bf(accR[t][i] + brv);
        }
    }
}

// GCN aggregate: grid-stride wave per node, 8-lane group per edge,
// 2-stage pipeline (records i+2, gathers i+1, compute i).
__global__ __launch_bounds__(256) void k_gcn_agg(const ushort* __restrict__ hb,
                                                 const int* __restrict__ rowptr,
                                                 const int2* __restrict__ eSW,
                                                 const float* __restrict__ dinv,
                                                 const float* __restrict__ b1,
                                                 ushort* __restrict__ hgb, int nN) {
    const int lane = threadIdx.x & 63;
    const int gwid = blockIdx.x * 4 + (threadIdx.x >> 6);
    const int nwv = gridDim.x * 4;
    const int g = lane >> 3, sub = lane & 7;
    const char* hB = (const char*)hb;
    const uint so = (uint)sub * 16u;

    for (int node = gwid; node < nN; node += nwv) {
        const float di = dinv[node];
        float acc[8] = {0.f, 0.f, 0.f, 0.f, 0.f, 0.f, 0.f, 0.f};
        const int beg = rowptr[node], endr = rowptr[node + 1];
        // pipeline prologue
        int e0 = beg + g, e1 = e0 + 8;
        bool cv0 = e0 < endr, cv1 = e1 < endr;
        int2 cq0 = cv0 ? eSW[e0] : make_int2(node, 0);
        int2 cq1 = cv1 ? eSW[e1] : make_int2(node, 0);
        uint4 cu0 = *(const uint4*)(hB + (((uint)cq0.x) << 7) + so);
        uint4 cu1 = *(const uint4*)(hB + (((uint)cq1.x) << 7) + so);
        e0 += 16; e1 += 16;
        bool nv0 = e0 < endr, nv1 = e1 < endr;
        int2 nq0 = nv0 ? eSW[e0] : make_int2(node, 0);
        int2 nq1 = nv1 ? eSW[e1] : make_int2(node, 0);
        for (int base = beg; base < endr; base += 16) {
            // gathers for i+1
            uint4 nu0 = *(const uint4*)(hB + (((uint)nq0.x) << 7) + so);
            uint4 nu1 = *(const uint4*)(hB + (((uint)nq1.x) << 7) + so);
            // records for i+2
            int f0 = base + 32 + g, f1 = f0 + 8;
            bool mv0 = f0 < endr, mv1 = f1 < endr;
            int2 mq0 = mv0 ? eSW[f0] : make_int2(node, 0);
            int2 mq1 = mv1 ? eSW[f1] : make_int2(node, 0);
            // compute iteration i
            float n0 = cv0 ? dinv[cq0.x] * __int_as_float(cq0.y) * di : 0.f;
            float n1 = cv1 ? dinv[cq1.x] * __int_as_float(cq1.y) * di : 0.f;
            float xa[8], xb[8];
            unp8(cu0, xa); unp8(cu1, xb);
#pragma unroll
            for (int j = 0; j < 8; j++)
                acc[j] = fmaf(n0, xa[j], fmaf(n1, xb[j], acc[j]));
            // rotate
            cq0 = nq0; cq1 = nq1; cv0 = nv0; cv1 = nv1;
            cu0 = nu0; cu1 = nu1;
            nq0 = mq0; nq1 = mq1; nv0 = mv0; nv1 = mv1;
        }
#pragma unroll
        for (int j = 0; j < 8; j++) {
            acc[j] += __shfl_xor(acc[j], 8, 64);
            acc[j] += __shfl_xor(acc[j], 16, 64);
            acc[j] += __shfl_xor(acc[j], 32, 64);
        }
        if (g == 0) {
            const int c0 = sub * 8;
            uint4 hv = *(const uint4*)(hB + (((uint)node) << 7) + so);
            float h8[8];
            unp8(hv, h8);
            float4 ba = *(const float4*)(b1 + c0);
            float4 bb = *(const float4*)(b1 + c0 + 4);
            float di2 = di * di;
            float o[8];
            o[0] = fmaxf(fmaf(di2, h8[0], acc[0]) + ba.x, 0.f);
            o[1] = fmaxf(fmaf(di2, h8[1], acc[1]) + ba.y, 0.f);
            o[2] = fmaxf(fmaf(di2, h8[2], acc[2]) + ba.z, 0.f);
            o[3] = fmaxf(fmaf(di2, h8[3], acc[3]) + ba.w, 0.f);
            o[4] = fmaxf(fmaf(di2, h8[4], acc[4]) + bb.x, 0.f);
            o[5] = fmaxf(fmaf(di2, h8[5], acc[5]) + bb.y, 0.f);
            o[6] = fmaxf(fmaf(di2, h8[6], acc[6]) + bb.z, 0.f);
            o[7] = fmaxf(fmaf(di2, h8[7], acc[7]) + bb.w, 0.f);
            uint4 ov;
            ov.x = pk2(o[0], o[1]);
            ov.y = pk2(o[2], o[3]);
            ov.z = pk2(o[4], o[5]);
            ov.w = pk2(o[6], o[7]);
            *(uint4*)((char*)hgb + (((uint)node) << 7) + so) = ov;
        }
    }
}

// Fused GATv2: grid-stride wave per node, 16-lane group per edge (8 ch/lane,
// head = sub>>2), 2-stage pipeline + abs-form leaky-relu.
// lrelu(v) = 0.6v + 0.4|v|  (exact in f32 for slope 0.2).
__global__ __launch_bounds__(256) void k_gat_fused(const uint* __restrict__ XL,
                                                   const uint* __restrict__ XR,
                                                   const int* __restrict__ rowptr,
                                                   const int2* __restrict__ eSW,
                                                   const float* __restrict__ lattr,
                                                   const float* __restrict__ We,
                                                   const float* __restrict__ att,
                                                   const float* __restrict__ bias_gat,
                                                   const float* __restrict__ x,
                                                   const float* __restrict__ Ws,
                                                   const float* __restrict__ bs,
                                                   const float* __restrict__ sgp,
                                                   float* __restrict__ out, int nN) {
    __shared__ float lds[4 * 608];
    const int lane = threadIdx.x & 63;
    const int wv = threadIdx.x >> 6;
    float* L = lds + wv * 608;
    const int g = lane >> 4, sub = lane & 15;
    const int hh = sub >> 2;
    const int c0 = sub * 8;
    const int gwid = blockIdx.x * 4 + wv;
    const int nwv = gridDim.x * 4;

    float We8[8], att8[8];
#pragma unroll
    for (int j = 0; j < 8; j++) { We8[j] = We[c0 + j]; att8[j] = att[c0 + j]; }
    const int cs = lane & 31, h0 = lane >> 5;
    const float bgv = bias_gat[cs], bsv = bs[cs], sgv = sgp[0];
    const char* XLb = (const char*)XL;
    const ushort* XLus = (const ushort*)XL;
    const uint so = (uint)sub * 16u;

    for (int node = gwid; node < nN; node += nwv) {
        uint4 ur = *(const uint4*)((const char*)XR + (((uint)node) << 8) + so);
        float xr8[8];
        unp8(ur, xr8);

        float acc[8] = {0.f, 0.f, 0.f, 0.f, 0.f, 0.f, 0.f, 0.f};
        float den = 0.f;
        const int beg = rowptr[node], endr = rowptr[node + 1];
        // pipeline prologue
        int e0 = beg + g, e1 = e0 + 4;
        bool cv0 = e0 < endr, cv1 = e1 < endr;
        int2 cq0 = cv0 ? eSW[e0] : make_int2(node, 0);
        int2 cq1 = cv1 ? eSW[e1] : make_int2(node, 0);
        uint4 cu0 = *(const uint4*)(XLb + (((uint)cq0.x) << 8) + so);
        uint4 cu1 = *(const uint4*)(XLb + (((uint)cq1.x) << 8) + so);
        e0 += 8; e1 += 8;
        bool nv0 = e0 < endr, nv1 = e1 < endr;
        int2 nq0 = nv0 ? eSW[e0] : make_int2(node, 0);
        int2 nq1 = nv1 ? eSW[e1] : make_int2(node, 0);
        for (int base = beg; base < endr; base += 8) {
            // gathers for i+1
            uint4 nu0 = *(const uint4*)(XLb + (((uint)nq0.x) << 8) + so);
            uint4 nu1 = *(const uint4*)(XLb + (((uint)nq1.x) << 8) + so);
            // records for i+2
            int f0 = base + 16 + g, f1 = f0 + 4;
            bool mv0 = f0 < endr, mv1 = f1 < endr;
            int2 mq0 = mv0 ? eSW[f0] : make_int2(node, 0);
            int2 mq1 = mv1 ? eSW[f1] : make_int2(node, 0);
            // compute iteration i
            float w0 = __int_as_float(cq0.y), w1 = __int_as_float(cq1.y);
            float xa[8], xb[8];
            unp8(cu0, xa); unp8(cu1, xb);
            float tl0 = 0.f, ta0 = 0.f, tl1 = 0.f, ta1 = 0.f;
#pragma unroll
            for (int j = 0; j < 8; j++) {
                float aj = att8[j], wj = We8[j], rj = xr8[j];
                float v0 = xa[j] + fmaf(w0, wj, rj);
                float v1 = xb[j] + fmaf(w1, wj, rj);
                tl0 = fmaf(v0, aj, tl0);
                ta0 = fmaf(fabsf(v0), aj, ta0);
                tl1 = fmaf(v1, aj, tl1);
                ta1 = fmaf(fabsf(v1), aj, ta1);
            }
            float t0 = red4(fmaf(0.4f, ta0, 0.6f * tl0));
            float t1 = red4(fmaf(0.4f, ta1, 0.6f * tl1));
            float ex0 = cv0 ? __expf(t0) : 0.f;
            float ex1 = cv1 ? __expf(t1) : 0.f;
            den += ex0 + ex1;
#pragma unroll
            for (int j = 0; j < 8; j++)
                acc[j] = fmaf(ex0, xa[j], fmaf(ex1, xb[j], acc[j]));
            // rotate
            cq0 = nq0; cq1 = nq1; cv0 = nv0; cv1 = nv1;
            cu0 = nu0; cu1 = nu1;
            nq0 = mq0; nq1 = mq1; nv0 = mv0; nv1 = mv1;
        }

        // self-loop alpha (identical across groups)
        float la = lattr[node];
        uint4 un = *(const uint4*)(XLb + (((uint)node) << 8) + so);
        float xn[8];
        unp8(un, xn);
        float tls = 0.f, tas = 0.f;
#pragma unroll
        for (int j = 0; j < 8; j++) {
            float v = xn[j] + fmaf(la, We8[j], xr8[j]);
            tls = fmaf(v, att8[j], tls);
            tas = fmaf(fabsf(v), att8[j], tas);
        }
        float ts = red4(fmaf(0.4f, tas, 0.6f * tls));
        float es = __expf(ts);

        // stash partials in wave-private LDS (stride 9)
#pragma unroll
        for (int j = 0; j < 8; j++) L[lane * 9 + j] = acc[j];
        if ((sub & 3) == 0) L[576 + g * 4 + hh] = den;
        if (g == 0 && (sub & 3) == 0) L[592 + hh] = es;

        // epilogue: head-mean + self-loop + skip
        float th = 0.f;
#pragma unroll
        for (int hd = 0; hd < 4; hd++) {
            int bl = hd * 4 + (cs >> 3);
            int j = cs & 7;
            float a = L[bl * 9 + j] + L[(16 + bl) * 9 + j] +
                      L[(32 + bl) * 9 + j] + L[(48 + bl) * 9 + j];
            float dn = L[576 + hd] + L[580 + hd] + L[584 + hd] + L[588 + hd];
            float eh = L[592 + hd];
            float xc = bfu(XLus[(size_t)node * 128 + hd * 32 + cs]);
            th += (a + eh * xc) / (dn + eh + 1e-16f);
        }
        const float4* xp = (const float4*)(x + (size_t)node * 64 + h0 * 32);
        const float4* wp = (const float4*)(Ws + (size_t)cs * 64 + h0 * 32);
        float sk = 0.f;
#pragma unroll
        for (int q = 0; q < 8; q++) {
            float4 xq = xp[q], wq = wp[q];
            sk += xq.x * wq.x + xq.y * wq.y + xq.z * wq.z + xq.w * wq.w;
        }
        sk += __shfl_xor(sk, 32, 64);
        float res = th * 0.25f + bgv + sgv * (sk + bsv);
        if (lane < 32) out[(size_t)node * 32 + cs] = res;
    }
}

// ---------- launch ----------
extern "C" void kernel_launch(void* const* d_in, const int* in_sizes, int n_in,
                              void* d_out, int out_size, void* d_ws, size_t ws_size,
                              hipStream_t stream) {
    const float* x        = (const float*)d_in[0];
    const int*   ei       = (const int*)d_in[1];
    const float* ew       = (const float*)d_in[2];
    const float* W1       = (const float*)d_in[3];
    const float* b1       = (const float*)d_in[4];
    const float* Wl       = (const float*)d_in[5];
    const float* bl       = (const float*)d_in[6];
    const float* Wr       = (const float*)d_in[7];
    const float* br       = (const float*)d_in[8];
    const float* We       = (const float*)d_in[9];
    const float* att      = (const float*)d_in[10];
    const float* bias_gat = (const float*)d_in[11];
    const float* Ws       = (const float*)d_in[12];
    const float* bs       = (const float*)d_in[13];
    const float* sg       = (const float*)d_in[14];

    const int N = in_sizes[0] / 64;
    const int E = in_sizes[2];
    const int* srcI = ei;
    const int* dstI = ei + E;
    const int nblk = (N + 255) / 256;
    const int Mt = (N + 15) / 16;

    char* p = (char*)d_ws;
    auto alloc = [&](size_t bytes) {
        void* r = (void*)p;
        p += (bytes + 255) & ~(size_t)255;
        return r;
    };
    int*    cnt    = (int*)alloc((size_t)N * 4);
    int*    fill   = (int*)alloc((size_t)N * 4);
    int*    rowptr = (int*)alloc((size_t)(N + 1) * 4);
    int*    bsum   = (int*)alloc((size_t)nblk * 4);
    int2*   eSW    = (int2*)alloc((size_t)E * 8);
    float*  sumw   = (float*)alloc((size_t)N * 4);
    float*  dinv   = (float*)alloc((size_t)N * 4);
    float*  lattr  = (float*)alloc((size_t)N * 4);
    ushort* hb     = (ushort*)alloc((size_t)Mt * 16 * 64 * 2);
    ushort* hgb    = (ushort*)alloc((size_t)Mt * 16 * 64 * 2);
    ushort* xl_bf  = (ushort*)alloc((size_t)Mt * 16 * 128 * 2);
    ushort* xr_bf  = (ushort*)alloc((size_t)Mt * 16 * 128 * 2);
    ushort* w1b    = (ushort*)alloc(4096 * 2);
    ushort* wlb    = (ushort*)alloc(8192 * 2);
    ushort* wrb    = (ushort*)alloc(8192 * 2);
    if ((size_t)(p - (char*)d_ws) > ws_size) return;

    hipMemsetAsync(cnt, 0, (size_t)N * 4, stream);
    hipMemsetAsync(fill, 0, (size_t)N * 4, stream);
    hipMemsetAsync(sumw, 0, (size_t)N * 4, stream);
    k_count<<<(E + 255) / 256, 256, 0, stream>>>(dstI, ew, cnt, sumw, E);
    k_bsum<<<nblk, 256, 0, stream>>>(cnt, bsum, N);
    k_bscan<<<1, 1024, 0, stream>>>(bsum, rowptr + N, nblk);
    k_rowptr<<<nblk, 256, 0, stream>>>(cnt, bsum, sumw, rowptr, dinv, lattr, N);
    k_scatter<<<(E + 255) / 256, 256, 0, stream>>>(srcI, dstI, ew, rowptr,
                                                   fill, eSW, E);
    k_cvtw<<<32, 256, 0, stream>>>(W1, Wl, Wr, w1b, wlb, wrb);
    k_gemm_x<<<(Mt + 3) / 4, 256, 0, stream>>>(x, w1b, hb, Mt);
    k_gcn_agg<<<2048, 256, 0, stream>>>(hb, rowptr, eSW, dinv, b1, hgb, N);
    k_gemm_lr<<<(Mt + 3) / 4, 256, 0, stream>>>(hgb, wlb, bl, wrb, br,
                                                xl_bf, xr_bf, Mt);
    k_gat_fused<<<1536, 256, 0, stream>>>((const uint*)xl_bf, (const uint*)xr_bf,
                                          rowptr, eSW, lattr, We, att,
                                          bias_gat, x, Ws, bs, sg,
                                          (float*)d_out, N);
}